// Round 2
// baseline (262.918 us; speedup 1.0000x reference)
//
#include <hip/hip_runtime.h>
#include <hip/hip_cooperative_groups.h>
#include <math.h>

namespace cg = cooperative_groups;

#define B_ 64
#define S_ 129
#define F_ 768
#define N3 192            // 3*B
#define GSZ 36864         // 192*192
#define GRID_MAIN 252     // 12 f-columns x 21 s-groups

// ws float offsets
#define WS_S1   0
#define WS_S2   49152
#define WS_SQ   98304
#define WS_PART 98560

// out float offsets
#define OUT_LOSS 6340608
#define OUT_NM   6340609
#define OUT_NV   6343681

typedef unsigned int uint;
using short8v = __attribute__((ext_vector_type(8))) short;
using float4v = __attribute__((ext_vector_type(4))) float;

// ---------------- bf16 helpers ----------------
__device__ __forceinline__ uint pack2(float a, float b) {
    uint ua = __float_as_uint(a);
    uint ub = __float_as_uint(b);
    uint ha = (ua + 0x7FFFu + ((ua >> 16) & 1u)) >> 16;
    uint hb = (ub + 0x7FFFu + ((ub >> 16) & 1u)) & 0xFFFF0000u;
    return hb | ha;
}

__device__ __forceinline__ void bf16_store8(char* lds, int row, int g,
                                            float4 v0, float4 v1) {
    uint4 H;
    H.x = pack2(v0.x, v0.y);
    H.y = pack2(v0.z, v0.w);
    H.z = pack2(v1.x, v1.y);
    H.w = pack2(v1.z, v1.w);
    *(uint4*)(lds + row * 128 + ((g ^ (row & 7)) << 4)) = H;
}

__device__ __forceinline__ float4 fma4(float4 a, float4 x, float4 b) {
    float4 r;
    r.x = fmaf(a.x, x.x, b.x); r.y = fmaf(a.y, x.y, b.y);
    r.z = fmaf(a.z, x.z, b.z); r.w = fmaf(a.w, x.w, b.w);
    return r;
}

// =================== COOPERATIVE ALL-IN-ONE KERNEL ===================
// 252 blocks x 512 threads, 1 block/CU. Phases separated by grid.sync():
//  P1: per-(b,f) sums over S (192 active blocks, 8-way S split)
//  P2: dom-stats + coef + x_mix/hg gen + MFMA Gram partials (identical to
//      the proven k_main body; EXCL partial per block)
//  P3a: block i reduces Gram row i from partials into LDS; sq[i] -> ws
//  P3b: triplet loss from LDS-resident row + sq[] (gram buffer eliminated)
__global__ __launch_bounds__(512, 2)
void k_all(const float* __restrict__ x, const float* __restrict__ hgn,
           const float* __restrict__ mean_buf, const float* __restrict__ var_buf,
           const float* __restrict__ lmda, const int* __restrict__ domain,
           const int* __restrict__ d_rand, const int* __restrict__ labels,
           float* __restrict__ xmix, float* __restrict__ out_nm,
           float* __restrict__ out_nv, float* __restrict__ out_loss,
           float* __restrict__ s1, float* __restrict__ s2,
           float* __restrict__ sqw, float* part) {
    __shared__ __align__(16) char LDS[32768];
    __shared__ float NMV[4][64];
    __shared__ float SVV[4][64];

    cg::grid_group grid = cg::this_grid();
    int tid = threadIdx.x;
    int bid = blockIdx.x;

    // ---------------- P1: stats ----------------
    if (bid < 192) {
        float4* r1 = (float4*)LDS;              // [512] = 8 KB
        float4* r2 = (float4*)(LDS + 8192);     // [512] = 8 KB
        int bb = bid / 3, fg = bid % 3;
        int c = tid & 63, sp = tid >> 6;        // 8-way S split
        int f = fg * 256 + c * 4;
        const float* p = x + (size_t)bb * S_ * F_ + f;
        int s0 = sp * 16;
        int se = s0 + 16 + (sp == 7 ? 1 : 0);
        float4 a1 = {0.f,0.f,0.f,0.f}, a2 = {0.f,0.f,0.f,0.f};
#pragma unroll 4
        for (int s = s0; s < se; ++s) {
            float4 v = *(const float4*)(p + s * F_);
            a1.x += v.x; a1.y += v.y; a1.z += v.z; a1.w += v.w;
            a2.x += v.x*v.x; a2.y += v.y*v.y; a2.z += v.z*v.z; a2.w += v.w*v.w;
        }
        r1[tid] = a1; r2[tid] = a2;
        __syncthreads();
        if (sp == 0) {
            float4 t1 = r1[c], t2 = r2[c];
#pragma unroll
            for (int k = 1; k < 8; ++k) {
                float4 u1 = r1[k * 64 + c], u2 = r2[k * 64 + c];
                t1.x += u1.x; t1.y += u1.y; t1.z += u1.z; t1.w += u1.w;
                t2.x += u2.x; t2.y += u2.y; t2.z += u2.z; t2.w += u2.w;
            }
            *(float4*)(s1 + bb * F_ + f) = t1;
            *(float4*)(s2 + bb * F_ + f) = t2;
        }
    }
    grid.sync();

    // ---------------- P2: main (identical structure to proven k_main) --------------
    {
        int fc = bid % 12, sb = bid / 12;
        int f0 = fc * 64;
        int b = tid >> 3, g = tid & 7;
        int w = tid >> 6;
        int wr = (w >> 2) * 96, wc = (w & 3) * 48;
        int lane = tid & 63, m = lane & 15, qd = lane >> 4;

        int s = sb;
        size_t goff = ((size_t)b * S_ + s) * F_ + f0 + (g << 3);
        float4 X0 = ((const float4*)(x + goff))[0];
        float4 X1 = ((const float4*)(x + goff))[1];
        float4 N0 = ((const float4*)(hgn + goff))[0];
        float4 N1 = ((const float4*)(hgn + goff))[1];

        if (tid < 256) {
            int d = tid & 3, fl = tid >> 2;
            int f = f0 + fl;
            float a1 = 0.f, a2 = 0.f, cnt = 0.f;
#pragma unroll 8
            for (int bb = 0; bb < B_; ++bb) {
                bool mk = (domain[bb] == d);
                a1  += mk ? s1[bb * F_ + f] : 0.f;
                a2  += mk ? s2[bb * F_ + f] : 0.f;
                cnt += mk ? 1.f : 0.f;
            }
            float nm, nv;
            if (cnt > 0.f) {
                float n = cnt * (float)S_;
                float mu = a1 / n;
                float var = (a2 - n * mu * mu) / fmaxf(n - 1.f, 1.f);
                nm = 0.9f * mean_buf[d * F_ + f] + 0.1f * mu;
                nv = 0.9f * var_buf[d * F_ + f] + 0.1f * var;
            } else {
                nm = mean_buf[d * F_ + f];
                nv = var_buf[d * F_ + f];
            }
            NMV[d][fl] = nm;
            SVV[d][fl] = sqrtf(nv + 1e-6f);
            if (sb == 0) { out_nm[d * F_ + f] = nm; out_nv[d * F_ + f] = nv; }
        }
        __syncthreads();

        int cb = b * F_ + f0 + (g << 3);
        float4 S1a = ((const float4*)(s1 + cb))[0], S1b = ((const float4*)(s1 + cb))[1];
        float4 S2a = ((const float4*)(s2 + cb))[0], S2b = ((const float4*)(s2 + cb))[1];
        int dm = domain[b];
        int dsd = (dm + d_rand[b]) & 3;              // D == 4
        float lam = lmda[b];
        float4 C1a, C1b, C0a, C0b, HMa, HMb, HSa, HSb;
#define COEF(SC1, SC2, FL, RC1, RC0, RHM, RHS) {            \
        float mu = (SC1) * (1.0f / (float)S_);              \
        float v  = ((SC2) - (float)S_ * mu * mu) * (1.0f / (float)(S_ - 1)); \
        float r  = rsqrtf(v + 1e-6f);                       \
        float sv = SVV[dsd][FL];                            \
        float rs = r * sv;                                  \
        RC1 = lam + (1.0f - lam) * rs;                      \
        RC0 = (1.0f - lam) * (NMV[dsd][FL] - mu * rs);      \
        RHM = NMV[dm][FL];                                  \
        RHS = SVV[dm][FL]; }
        {
            int fb = g << 3;
            COEF(S1a.x, S2a.x, fb + 0, C1a.x, C0a.x, HMa.x, HSa.x);
            COEF(S1a.y, S2a.y, fb + 1, C1a.y, C0a.y, HMa.y, HSa.y);
            COEF(S1a.z, S2a.z, fb + 2, C1a.z, C0a.z, HMa.z, HSa.z);
            COEF(S1a.w, S2a.w, fb + 3, C1a.w, C0a.w, HMa.w, HSa.w);
            COEF(S1b.x, S2b.x, fb + 4, C1b.x, C0b.x, HMb.x, HSb.x);
            COEF(S1b.y, S2b.y, fb + 5, C1b.y, C0b.y, HMb.y, HSb.y);
            COEF(S1b.z, S2b.z, fb + 6, C1b.z, C0b.z, HMb.z, HSb.z);
            COEF(S1b.w, S2b.w, fb + 7, C1b.w, C0b.w, HMb.w, HSb.w);
        }
#undef COEF

        float4v acc[6][3];
#pragma unroll
        for (int i = 0; i < 6; ++i)
#pragma unroll
            for (int j = 0; j < 3; ++j)
                acc[i][j] = (float4v){0.f, 0.f, 0.f, 0.f};

        for (; s < S_; s += 21) {
            float4 M0 = fma4(C1a, X0, C0a);
            float4 M1 = fma4(C1b, X1, C0b);
            ((float4*)(xmix + goff))[0] = M0;
            ((float4*)(xmix + goff))[1] = M1;
            float4 H0 = fma4(HSa, N0, HMa);
            float4 H1 = fma4(HSb, N1, HMb);

            bf16_store8(LDS, b, g, X0, X1);
            bf16_store8(LDS, 64 + b, g, M0, M1);
            bf16_store8(LDS, 128 + b, g, H0, H1);
            __syncthreads();

            int sn = s + 21;
            if (sn < S_) {
                goff = ((size_t)b * S_ + sn) * F_ + f0 + (g << 3);
                X0 = ((const float4*)(x + goff))[0];
                X1 = ((const float4*)(x + goff))[1];
                N0 = ((const float4*)(hgn + goff))[0];
                N1 = ((const float4*)(hgn + goff))[1];
            }

#pragma unroll
            for (int t = 0; t < 2; ++t) {
                short8v A[6];
#pragma unroll
                for (int i = 0; i < 6; ++i) {
                    int row = wr + i * 16 + m;
                    int go = (((t << 2) + qd) ^ (row & 7)) << 4;
                    A[i] = *(const short8v*)(LDS + row * 128 + go);
                }
#pragma unroll
                for (int j = 0; j < 3; ++j) {
                    int row = wc + j * 16 + m;
                    int go = (((t << 2) + qd) ^ (row & 7)) << 4;
                    short8v Bv = *(const short8v*)(LDS + row * 128 + go);
#pragma unroll
                    for (int i = 0; i < 6; ++i)
                        acc[i][j] = __builtin_amdgcn_mfma_f32_16x16x32_bf16(A[i], Bv, acc[i][j], 0, 0, 0);
                }
            }
            __syncthreads();
        }

        // epilogue: LDS-transpose each 16-row band, store coalesced float4
        float* T = (float*)LDS;                      // [32][196] f32
        const int PADW = 196;
        float* dst = part + (size_t)bid * GSZ;       // EXCL: one slice per block
        int lrb = (wr ? 16 : 0) + (qd << 2);
        int lr2 = tid >> 4;
#pragma unroll
        for (int i = 0; i < 6; ++i) {
            __syncthreads();
#pragma unroll
            for (int j = 0; j < 3; ++j) {
                int colb = wc + j * 16 + m;
#pragma unroll
                for (int r = 0; r < 4; ++r)
                    T[(lrb + r) * PADW + colb] = acc[i][j][r];
            }
            __syncthreads();
            int grow = i * 16 + (lr2 & 15) + (lr2 >> 4) * 96;
#pragma unroll
            for (int k = 0; k < 3; ++k) {
                int c4 = k * 16 + (tid & 15);
                float4 vv = *(const float4*)&T[lr2 * PADW + (c4 << 2)];
                *(float4*)(dst + grow * N3 + (c4 << 2)) = vv;
            }
        }
    }
    grid.sync();

    // ---------------- P3a: reduce Gram row bid from partials into LDS --------------
    float* ROW = (float*)LDS;                        // [2][192]
    if (bid == 0 && tid == 0) out_loss[0] = 0.0f;
    if (bid < N3 && tid < 384) {
        int c = tid % 192, half = tid / 192;
        float sacc = 0.f;
#pragma unroll 8
        for (int p = half; p < GRID_MAIN; p += 2)
            sacc += part[(size_t)p * GSZ + bid * N3 + c];
        ROW[half * 192 + c] = sacc;
    }
    __syncthreads();
    if (bid < N3 && tid < 192) {
        float rv = ROW[tid] + ROW[192 + tid];
        ROW[tid] = rv;
        if (tid == bid) sqw[bid] = rv;               // diagonal -> sq
    }
    grid.sync();

    // ---------------- P3b: triplet loss from LDS row + sq[] ----------------
    if (bid < N3) {
        float* SQS = (float*)(LDS + 2048);
        int*   LN  = (int*)(LDS + 2048 + 768);
        float* APW = (float*)(LDS + 4096);
        float* ANW = (float*)(LDS + 4096 + 16);
        if (tid < N3) {
            SQS[tid] = sqw[tid];
            LN[tid] = (tid < 128) ? labels[tid & 63] : -1;
        }
        __syncthreads();
        float ap = -1e30f, an = 1e30f;
        if (tid < N3) {
            int li = LN[bid];
            float d2 = SQS[bid] + SQS[tid] - 2.0f * ROW[tid];
            float dist = sqrtf(fmaxf(d2, 1e-12f));
            bool pos = (li == LN[tid]);
            ap = pos ? dist : -1e30f;
            an = pos ? 1e30f : dist;
        }
#pragma unroll
        for (int off = 32; off; off >>= 1) {
            ap = fmaxf(ap, __shfl_xor(ap, off));
            an = fminf(an, __shfl_xor(an, off));
        }
        if (tid < N3 && (tid & 63) == 0) { APW[tid >> 6] = ap; ANW[tid >> 6] = an; }
        __syncthreads();
        if (tid == 0) {
            float a = fmaxf(fmaxf(APW[0], APW[1]), APW[2]);
            float n = fminf(fminf(ANW[0], ANW[1]), ANW[2]);
            float xv = a - n;
            float sp = fmaxf(xv, 0.0f) + log1pf(expf(-fabsf(xv)));
            atomicAdd(out_loss, sp * (1.0f / (float)N3));
        }
    }
}

// =================== FALLBACK: proven 4-kernel path (r1) ===================
__global__ void k_stats(const float* __restrict__ x,
                        float* __restrict__ s1, float* __restrict__ s2,
                        float* __restrict__ out_loss) {
    __shared__ float4 r1[256], r2[256];
    if (blockIdx.x == 0 && threadIdx.x == 0) out_loss[0] = 0.0f;
    int b = blockIdx.x / 3, fg = blockIdx.x % 3;
    int c = threadIdx.x & 63, sp = threadIdx.x >> 6;
    int f = fg * 256 + c * 4;
    const float* p = x + (size_t)b * S_ * F_ + f;
    int s0 = sp * 32;
    int se = s0 + 32 + (sp == 3 ? 1 : 0);
    float4 a1 = {0.f,0.f,0.f,0.f}, a2 = {0.f,0.f,0.f,0.f};
#pragma unroll 4
    for (int s = s0; s < se; ++s) {
        float4 v = *(const float4*)(p + s * F_);
        a1.x += v.x; a1.y += v.y; a1.z += v.z; a1.w += v.w;
        a2.x += v.x*v.x; a2.y += v.y*v.y; a2.z += v.z*v.z; a2.w += v.w*v.w;
    }
    r1[threadIdx.x] = a1; r2[threadIdx.x] = a2;
    __syncthreads();
    if (sp == 0) {
        float4 t1 = r1[c], t2 = r2[c];
#pragma unroll
        for (int k = 1; k < 4; ++k) {
            float4 u1 = r1[k * 64 + c], u2 = r2[k * 64 + c];
            t1.x += u1.x; t1.y += u1.y; t1.z += u1.z; t1.w += u1.w;
            t2.x += u2.x; t2.y += u2.y; t2.z += u2.z; t2.w += u2.w;
        }
        *(float4*)(s1 + b * F_ + f) = t1;
        *(float4*)(s2 + b * F_ + f) = t2;
    }
}

template <bool EXCL>
__global__ __launch_bounds__(512, 2)
void k_main(const float* __restrict__ x, const float* __restrict__ hgn,
            const float* __restrict__ s1, const float* __restrict__ s2,
            const float* __restrict__ mean_buf, const float* __restrict__ var_buf,
            const float* __restrict__ lmda, const int* __restrict__ domain,
            const int* __restrict__ d_rand,
            float* __restrict__ xmix, float* __restrict__ out_nm,
            float* __restrict__ out_nv,
            float* part, int npart) {
    __shared__ __align__(16) char LDS[25088];
    __shared__ float NMV[4][64];
    __shared__ float SVV[4][64];

    int tid = threadIdx.x;
    int bid = blockIdx.x;
    int fc = bid % 12, sb = bid / 12;
    int f0 = fc * 64;
    int b = tid >> 3, g = tid & 7;
    int w = tid >> 6;
    int wr = (w >> 2) * 96, wc = (w & 3) * 48;
    int lane = tid & 63, m = lane & 15, qd = lane >> 4;

    int s = sb;
    size_t goff = ((size_t)b * S_ + s) * F_ + f0 + (g << 3);
    float4 X0 = ((const float4*)(x + goff))[0];
    float4 X1 = ((const float4*)(x + goff))[1];
    float4 N0 = ((const float4*)(hgn + goff))[0];
    float4 N1 = ((const float4*)(hgn + goff))[1];

    if (tid < 256) {
        int d = tid & 3, fl = tid >> 2;
        int f = f0 + fl;
        float a1 = 0.f, a2 = 0.f, cnt = 0.f;
#pragma unroll 8
        for (int bb = 0; bb < B_; ++bb) {
            bool mk = (domain[bb] == d);
            a1  += mk ? s1[bb * F_ + f] : 0.f;
            a2  += mk ? s2[bb * F_ + f] : 0.f;
            cnt += mk ? 1.f : 0.f;
        }
        float nm, nv;
        if (cnt > 0.f) {
            float n = cnt * (float)S_;
            float mu = a1 / n;
            float var = (a2 - n * mu * mu) / fmaxf(n - 1.f, 1.f);
            nm = 0.9f * mean_buf[d * F_ + f] + 0.1f * mu;
            nv = 0.9f * var_buf[d * F_ + f] + 0.1f * var;
        } else {
            nm = mean_buf[d * F_ + f];
            nv = var_buf[d * F_ + f];
        }
        NMV[d][fl] = nm;
        SVV[d][fl] = sqrtf(nv + 1e-6f);
        if (sb == 0) { out_nm[d * F_ + f] = nm; out_nv[d * F_ + f] = nv; }
    }
    __syncthreads();

    int cb = b * F_ + f0 + (g << 3);
    float4 S1a = ((const float4*)(s1 + cb))[0], S1b = ((const float4*)(s1 + cb))[1];
    float4 S2a = ((const float4*)(s2 + cb))[0], S2b = ((const float4*)(s2 + cb))[1];
    int dm = domain[b];
    int dsd = (dm + d_rand[b]) & 3;
    float lam = lmda[b];
    float4 C1a, C1b, C0a, C0b, HMa, HMb, HSa, HSb;
#define COEF(SC1, SC2, FL, RC1, RC0, RHM, RHS) {            \
        float mu = (SC1) * (1.0f / (float)S_);              \
        float v  = ((SC2) - (float)S_ * mu * mu) * (1.0f / (float)(S_ - 1)); \
        float r  = rsqrtf(v + 1e-6f);                       \
        float sv = SVV[dsd][FL];                            \
        float rs = r * sv;                                  \
        RC1 = lam + (1.0f - lam) * rs;                      \
        RC0 = (1.0f - lam) * (NMV[dsd][FL] - mu * rs);      \
        RHM = NMV[dm][FL];                                  \
        RHS = SVV[dm][FL]; }
    {
        int fb = g << 3;
        COEF(S1a.x, S2a.x, fb + 0, C1a.x, C0a.x, HMa.x, HSa.x);
        COEF(S1a.y, S2a.y, fb + 1, C1a.y, C0a.y, HMa.y, HSa.y);
        COEF(S1a.z, S2a.z, fb + 2, C1a.z, C0a.z, HMa.z, HSa.z);
        COEF(S1a.w, S2a.w, fb + 3, C1a.w, C0a.w, HMa.w, HSa.w);
        COEF(S1b.x, S2b.x, fb + 4, C1b.x, C0b.x, HMb.x, HSb.x);
        COEF(S1b.y, S2b.y, fb + 5, C1b.y, C0b.y, HMb.y, HSb.y);
        COEF(S1b.z, S2b.z, fb + 6, C1b.z, C0b.z, HMb.z, HSb.z);
        COEF(S1b.w, S2b.w, fb + 7, C1b.w, C0b.w, HMb.w, HSb.w);
    }
#undef COEF

    float4v acc[6][3];
#pragma unroll
    for (int i = 0; i < 6; ++i)
#pragma unroll
        for (int j = 0; j < 3; ++j)
            acc[i][j] = (float4v){0.f, 0.f, 0.f, 0.f};

    for (; s < S_; s += 21) {
        float4 M0 = fma4(C1a, X0, C0a);
        float4 M1 = fma4(C1b, X1, C0b);
        ((float4*)(xmix + goff))[0] = M0;
        ((float4*)(xmix + goff))[1] = M1;
        float4 H0 = fma4(HSa, N0, HMa);
        float4 H1 = fma4(HSb, N1, HMb);

        bf16_store8(LDS, b, g, X0, X1);
        bf16_store8(LDS, 64 + b, g, M0, M1);
        bf16_store8(LDS, 128 + b, g, H0, H1);
        __syncthreads();

        int sn = s + 21;
        if (sn < S_) {
            goff = ((size_t)b * S_ + sn) * F_ + f0 + (g << 3);
            X0 = ((const float4*)(x + goff))[0];
            X1 = ((const float4*)(x + goff))[1];
            N0 = ((const float4*)(hgn + goff))[0];
            N1 = ((const float4*)(hgn + goff))[1];
        }

#pragma unroll
        for (int t = 0; t < 2; ++t) {
            short8v A[6];
#pragma unroll
            for (int i = 0; i < 6; ++i) {
                int row = wr + i * 16 + m;
                int go = (((t << 2) + qd) ^ (row & 7)) << 4;
                A[i] = *(const short8v*)(LDS + row * 128 + go);
            }
#pragma unroll
            for (int j = 0; j < 3; ++j) {
                int row = wc + j * 16 + m;
                int go = (((t << 2) + qd) ^ (row & 7)) << 4;
                short8v Bv = *(const short8v*)(LDS + row * 128 + go);
#pragma unroll
                for (int i = 0; i < 6; ++i)
                    acc[i][j] = __builtin_amdgcn_mfma_f32_16x16x32_bf16(A[i], Bv, acc[i][j], 0, 0, 0);
            }
        }
        __syncthreads();
    }

    float* T = (float*)LDS;
    const int PADW = 196;
    float* dst = part + (size_t)(bid % npart) * GSZ;
    int lrb = (wr ? 16 : 0) + (qd << 2);
    int lr2 = tid >> 4;
#pragma unroll
    for (int i = 0; i < 6; ++i) {
        __syncthreads();
#pragma unroll
        for (int j = 0; j < 3; ++j) {
            int colb = wc + j * 16 + m;
#pragma unroll
            for (int r = 0; r < 4; ++r)
                T[(lrb + r) * PADW + colb] = acc[i][j][r];
        }
        __syncthreads();
        int grow = i * 16 + (lr2 & 15) + (lr2 >> 4) * 96;
#pragma unroll
        for (int k = 0; k < 3; ++k) {
            int c4 = k * 16 + (tid & 15);
            float4 vv = *(const float4*)&T[lr2 * PADW + (c4 << 2)];
            int o = grow * N3 + (c4 << 2);
            if (EXCL) {
                *(float4*)(dst + o) = vv;
            } else {
                atomicAdd(dst + o + 0, vv.x);
                atomicAdd(dst + o + 1, vv.y);
                atomicAdd(dst + o + 2, vv.z);
                atomicAdd(dst + o + 3, vv.w);
            }
        }
    }
}

__global__ void k_red(const float* __restrict__ part, float* __restrict__ gram, int npart) {
    int j = blockIdx.x * 256 + threadIdx.x;
    float s = 0.0f;
#pragma unroll 8
    for (int p = 0; p < npart; ++p) s += part[(size_t)p * GSZ + j];
    gram[j] = s;
}

__global__ void k_loss(const float* __restrict__ gram, const int* __restrict__ labels,
                       float* __restrict__ out_loss) {
    __shared__ float sq[N3];
    __shared__ int ln[N3];
    int i = blockIdx.x, lane = threadIdx.x;
    for (int k = lane; k < N3; k += 64) {
        sq[k] = gram[k * (N3 + 1)];
        ln[k] = (k < 128) ? labels[k & 63] : -1;
    }
    __syncthreads();
    int li = ln[i];
    float si = sq[i];
    float ap = -1e30f, an = 1e30f;
    for (int j = lane; j < N3; j += 64) {
        float d2 = si + sq[j] - 2.0f * gram[i * N3 + j];
        float dist = sqrtf(fmaxf(d2, 1e-12f));
        bool pos = (li == ln[j]);
        ap = pos ? fmaxf(ap, dist) : ap;
        an = pos ? an : fminf(an, dist);
    }
#pragma unroll
    for (int off = 32; off; off >>= 1) {
        ap = fmaxf(ap, __shfl_xor(ap, off));
        an = fminf(an, __shfl_xor(an, off));
    }
    if (lane == 0) {
        float xv = ap - an;
        float sp = fmaxf(xv, 0.0f) + log1pf(expf(-fabsf(xv)));
        atomicAdd(out_loss, sp * (1.0f / (float)N3));
    }
}

extern "C" void kernel_launch(void* const* d_in, const int* in_sizes, int n_in,
                              void* d_out, int out_size, void* d_ws, size_t ws_size,
                              hipStream_t stream) {
    const float* x        = (const float*)d_in[0];
    const float* lmda     = (const float*)d_in[1];
    const float* mean_buf = (const float*)d_in[2];
    const float* var_buf  = (const float*)d_in[3];
    const float* hgn      = (const float*)d_in[4];
    const int*   labels   = (const int*)d_in[5];
    const int*   domain   = (const int*)d_in[6];
    const int*   d_rand   = (const int*)d_in[7];
    float* out = (float*)d_out;
    float* ws  = (float*)d_ws;

    long ws_floats = (long)(ws_size / 4);
    bool coop_ok = false;
    if (ws_floats >= WS_PART + (long)GRID_MAIN * GSZ) {
        float* xmix = out;
        float* onm  = out + OUT_NM;
        float* onv  = out + OUT_NV;
        float* ols  = out + OUT_LOSS;
        float* s1p  = ws + WS_S1;
        float* s2p  = ws + WS_S2;
        float* sqp  = ws + WS_SQ;
        float* pp   = ws + WS_PART;
        void* args[] = {(void*)&x, (void*)&hgn, (void*)&mean_buf, (void*)&var_buf,
                        (void*)&lmda, (void*)&domain, (void*)&d_rand, (void*)&labels,
                        (void*)&xmix, (void*)&onm, (void*)&onv, (void*)&ols,
                        (void*)&s1p, (void*)&s2p, (void*)&sqp, (void*)&pp};
        hipError_t e = hipLaunchCooperativeKernel((void*)k_all, dim3(GRID_MAIN),
                                                  dim3(512), args, 0, stream);
        coop_ok = (e == hipSuccess);
    }
    if (coop_ok) return;

    // -------- fallback: proven 4-kernel path --------
    long avail = ws_floats - WS_PART;
    int npart = (int)(avail / GSZ) - 1;
    if (npart < 1) npart = 1;
    if (npart > GRID_MAIN) npart = GRID_MAIN;
    bool excl = (npart == GRID_MAIN);
    float* part = ws + WS_PART;
    float* gram = ws + WS_PART + (size_t)npart * GSZ;

    k_stats<<<dim3(192), dim3(256), 0, stream>>>(x, ws + WS_S1, ws + WS_S2,
                                                 out + OUT_LOSS);
    if (!excl) {
        hipMemsetAsync(part, 0, (size_t)npart * GSZ * 4, stream);
    }
    if (excl) {
        k_main<true><<<dim3(GRID_MAIN), dim3(512), 0, stream>>>(
            x, hgn, ws + WS_S1, ws + WS_S2, mean_buf, var_buf,
            lmda, domain, d_rand,
            out, out + OUT_NM, out + OUT_NV, part, npart);
    } else {
        k_main<false><<<dim3(GRID_MAIN), dim3(512), 0, stream>>>(
            x, hgn, ws + WS_S1, ws + WS_S2, mean_buf, var_buf,
            lmda, domain, d_rand,
            out, out + OUT_NM, out + OUT_NV, part, npart);
    }
    k_red<<<dim3(144), dim3(256), 0, stream>>>(part, gram, npart);
    k_loss<<<dim3(N3), dim3(64), 0, stream>>>(gram, labels, out + OUT_LOSS);
}

// Round 4
// 141.875 us; speedup vs baseline: 1.8532x; 1.8532x over previous
//
#include <hip/hip_runtime.h>
#include <math.h>

#define B_ 64
#define S_ 129
#define F_ 768
#define N3 192            // 3*B
#define GSZ 36864         // 192*192
#define GRID_MAIN 252     // 12 f-columns x 21 s-groups

// ws float offsets
#define WS_S1   0
#define WS_S2   49152
#define WS_SQ   98304     // 192 floats (diag of gram), padded to 256
#define WS_PART 98560

// out float offsets
#define OUT_LOSS 6340608
#define OUT_NM   6340609
#define OUT_NV   6343681

typedef unsigned int uint;
using short8v = __attribute__((ext_vector_type(8))) short;
using float4v = __attribute__((ext_vector_type(4))) float;

// ---------------- bf16 helpers ----------------
__device__ __forceinline__ uint pack2(float a, float b) {
    uint ua = __float_as_uint(a);
    uint ub = __float_as_uint(b);
    uint ha = (ua + 0x7FFFu + ((ua >> 16) & 1u)) >> 16;
    uint hb = (ub + 0x7FFFu + ((ub >> 16) & 1u)) & 0xFFFF0000u;
    return hb | ha;
}

__device__ __forceinline__ void bf16_store8(char* lds, int row, int g,
                                            float4 v0, float4 v1) {
    uint4 H;
    H.x = pack2(v0.x, v0.y);
    H.y = pack2(v0.z, v0.w);
    H.z = pack2(v1.x, v1.y);
    H.w = pack2(v1.z, v1.w);
    *(uint4*)(lds + row * 128 + ((g ^ (row & 7)) << 4)) = H;
}

__device__ __forceinline__ float4 fma4(float4 a, float4 x, float4 b) {
    float4 r;
    r.x = fmaf(a.x, x.x, b.x); r.y = fmaf(a.y, x.y, b.y);
    r.z = fmaf(a.z, x.z, b.z); r.w = fmaf(a.w, x.w, b.w);
    return r;
}

// ---------------- K1: per-(b,f) sums over S, 8-way S-split + LDS reduce ------------
// Also zeroes sqw (gram diagonal accumulator) and out_loss.
__global__ void k_stats(const float* __restrict__ x,
                        float* __restrict__ s1, float* __restrict__ s2,
                        float* __restrict__ sqw, float* __restrict__ out_loss) {
    __shared__ float4 r1[512], r2[512];
    if (blockIdx.x == 0) {
        if (threadIdx.x == 0) out_loss[0] = 0.0f;
        if (threadIdx.x < N3) sqw[threadIdx.x] = 0.0f;
    }
    int b = blockIdx.x / 3, fg = blockIdx.x % 3;
    int c = threadIdx.x & 63, sp = threadIdx.x >> 6;   // 8-way S split
    int f = fg * 256 + c * 4;
    const float* p = x + (size_t)b * S_ * F_ + f;
    int s0 = sp * 16;
    int se = s0 + 16 + (sp == 7 ? 1 : 0);
    float4 a1 = {0.f,0.f,0.f,0.f}, a2 = {0.f,0.f,0.f,0.f};
#pragma unroll 4
    for (int s = s0; s < se; ++s) {
        float4 v = *(const float4*)(p + s * F_);
        a1.x += v.x; a1.y += v.y; a1.z += v.z; a1.w += v.w;
        a2.x += v.x*v.x; a2.y += v.y*v.y; a2.z += v.z*v.z; a2.w += v.w*v.w;
    }
    r1[threadIdx.x] = a1; r2[threadIdx.x] = a2;
    __syncthreads();
    if (sp == 0) {
        float4 t1 = r1[c], t2 = r2[c];
#pragma unroll
        for (int k = 1; k < 8; ++k) {
            float4 u1 = r1[k * 64 + c], u2 = r2[k * 64 + c];
            t1.x += u1.x; t1.y += u1.y; t1.z += u1.z; t1.w += u1.w;
            t2.x += u2.x; t2.y += u2.y; t2.z += u2.z; t2.w += u2.w;
        }
        *(float4*)(s1 + b * F_ + f) = t1;
        *(float4*)(s2 + b * F_ + f) = t2;
    }
}

// ---------------- K2: fused dom-stats + coef + x_mix/hg gen + MFMA Gram -------------
// 252 blocks x 512 threads, 1 block/CU. Depth-2 register prefetch on x/hgn (two
// named A/B buffers, static unroll-by-2 — r9 lesson: no runtime-indexed buffers).
// Epilogue additionally atomicAdds the partial-Gram diagonal into sqw so the
// loss kernel can be merged with the row reduction (k_red eliminated).
template <bool EXCL>
__global__ __launch_bounds__(512, 2)
void k_main(const float* __restrict__ x, const float* __restrict__ hgn,
            const float* __restrict__ s1, const float* __restrict__ s2,
            const float* __restrict__ mean_buf, const float* __restrict__ var_buf,
            const float* __restrict__ lmda, const int* __restrict__ domain,
            const int* __restrict__ d_rand,
            float* __restrict__ xmix, float* __restrict__ out_nm,
            float* __restrict__ out_nv,
            float* part, float* __restrict__ sqw, int npart) {
    __shared__ __align__(16) char LDS[25088];   // main: 192x128B bf16; epi: 32x196 f32
    __shared__ float NMV[4][64];
    __shared__ float SVV[4][64];

    int tid = threadIdx.x;
    int bid = blockIdx.x;
    int fc = bid % 12, sb = bid / 12;
    int f0 = fc * 64;
    int b = tid >> 3, g = tid & 7;
    int w = tid >> 6;
    int wr = (w >> 2) * 96, wc = (w & 3) * 48;
    int lane = tid & 63, m = lane & 15, qd = lane >> 4;

    // depth-2 prefetch: preload chunks sb (A) and sb+21 (B) before the prologue
    size_t gA = ((size_t)b * S_ + sb) * F_ + f0 + (g << 3);
    float4 XA0 = ((const float4*)(x + gA))[0];
    float4 XA1 = ((const float4*)(x + gA))[1];
    float4 NA0 = ((const float4*)(hgn + gA))[0];
    float4 NA1 = ((const float4*)(hgn + gA))[1];
    size_t gB = ((size_t)b * S_ + sb + 21) * F_ + f0 + (g << 3);  // sb+21 <= 41 < S_
    float4 XB0 = ((const float4*)(x + gB))[0];
    float4 XB1 = ((const float4*)(x + gB))[1];
    float4 NB0 = ((const float4*)(hgn + gB))[0];
    float4 NB1 = ((const float4*)(hgn + gB))[1];

    // ---- folded k_dom: per-(d,f) EMA stats for this block's f-column ----
    if (tid < 256) {
        int d = tid & 3, fl = tid >> 2;
        int f = f0 + fl;
        float a1 = 0.f, a2 = 0.f, cnt = 0.f;
#pragma unroll 8
        for (int bb = 0; bb < B_; ++bb) {
            bool mk = (domain[bb] == d);
            a1  += mk ? s1[bb * F_ + f] : 0.f;
            a2  += mk ? s2[bb * F_ + f] : 0.f;
            cnt += mk ? 1.f : 0.f;
        }
        float nm, nv;
        if (cnt > 0.f) {
            float n = cnt * (float)S_;
            float mu = a1 / n;
            float var = (a2 - n * mu * mu) / fmaxf(n - 1.f, 1.f);
            nm = 0.9f * mean_buf[d * F_ + f] + 0.1f * mu;
            nv = 0.9f * var_buf[d * F_ + f] + 0.1f * var;
        } else {
            nm = mean_buf[d * F_ + f];
            nv = var_buf[d * F_ + f];
        }
        NMV[d][fl] = nm;
        SVV[d][fl] = sqrtf(nv + 1e-6f);
        if (sb == 0) { out_nm[d * F_ + f] = nm; out_nv[d * F_ + f] = nv; }
    }
    __syncthreads();

    // ---- folded k_coef: per-thread mix/hg coefficients, held in regs all kernel ----
    int cb = b * F_ + f0 + (g << 3);
    float4 S1a = ((const float4*)(s1 + cb))[0], S1b = ((const float4*)(s1 + cb))[1];
    float4 S2a = ((const float4*)(s2 + cb))[0], S2b = ((const float4*)(s2 + cb))[1];
    int dm = domain[b];
    int dsd = (dm + d_rand[b]) & 3;              // D == 4
    float lam = lmda[b];
    float4 C1a, C1b, C0a, C0b, HMa, HMb, HSa, HSb;
#define COEF(SC1, SC2, FL, RC1, RC0, RHM, RHS) {            \
        float mu = (SC1) * (1.0f / (float)S_);              \
        float v  = ((SC2) - (float)S_ * mu * mu) * (1.0f / (float)(S_ - 1)); \
        float r  = rsqrtf(v + 1e-6f);                       \
        float sv = SVV[dsd][FL];                            \
        float rs = r * sv;                                  \
        RC1 = lam + (1.0f - lam) * rs;                      \
        RC0 = (1.0f - lam) * (NMV[dsd][FL] - mu * rs);      \
        RHM = NMV[dm][FL];                                  \
        RHS = SVV[dm][FL]; }
    {
        int fb = g << 3;
        COEF(S1a.x, S2a.x, fb + 0, C1a.x, C0a.x, HMa.x, HSa.x);
        COEF(S1a.y, S2a.y, fb + 1, C1a.y, C0a.y, HMa.y, HSa.y);
        COEF(S1a.z, S2a.z, fb + 2, C1a.z, C0a.z, HMa.z, HSa.z);
        COEF(S1a.w, S2a.w, fb + 3, C1a.w, C0a.w, HMa.w, HSa.w);
        COEF(S1b.x, S2b.x, fb + 4, C1b.x, C0b.x, HMb.x, HSb.x);
        COEF(S1b.y, S2b.y, fb + 5, C1b.y, C0b.y, HMb.y, HSb.y);
        COEF(S1b.z, S2b.z, fb + 6, C1b.z, C0b.z, HMb.z, HSb.z);
        COEF(S1b.w, S2b.w, fb + 7, C1b.w, C0b.w, HMb.w, HSb.w);
    }
#undef COEF

    float4v acc[6][3];
#pragma unroll
    for (int i = 0; i < 6; ++i)
#pragma unroll
        for (int j = 0; j < 3; ++j)
            acc[i][j] = (float4v){0.f, 0.f, 0.f, 0.f};

#define MFMA_SECTION                                                         \
        _Pragma("unroll")                                                    \
        for (int t = 0; t < 2; ++t) {                                        \
            short8v A[6];                                                    \
            _Pragma("unroll")                                                \
            for (int i = 0; i < 6; ++i) {                                    \
                int row = wr + i * 16 + m;                                   \
                int go = (((t << 2) + qd) ^ (row & 7)) << 4;                 \
                A[i] = *(const short8v*)(LDS + row * 128 + go);              \
            }                                                                \
            _Pragma("unroll")                                                \
            for (int j = 0; j < 3; ++j) {                                    \
                int row = wc + j * 16 + m;                                   \
                int go = (((t << 2) + qd) ^ (row & 7)) << 4;                 \
                short8v Bv = *(const short8v*)(LDS + row * 128 + go);        \
                _Pragma("unroll")                                            \
                for (int i = 0; i < 6; ++i)                                  \
                    acc[i][j] = __builtin_amdgcn_mfma_f32_16x16x32_bf16(     \
                        A[i], Bv, acc[i][j], 0, 0, 0);                       \
            }                                                                \
        }

#define DO_CHUNK(X0_, X1_, N0_, N1_, GOFF_, SNXT_)                           \
    {                                                                        \
        float4 M0 = fma4(C1a, X0_, C0a);                                     \
        float4 M1 = fma4(C1b, X1_, C0b);                                     \
        ((float4*)(xmix + GOFF_))[0] = M0;                                   \
        ((float4*)(xmix + GOFF_))[1] = M1;                                   \
        float4 H0 = fma4(HSa, N0_, HMa);                                     \
        float4 H1 = fma4(HSb, N1_, HMb);                                     \
        bf16_store8(LDS, b, g, X0_, X1_);                                    \
        bf16_store8(LDS, 64 + b, g, M0, M1);                                 \
        bf16_store8(LDS, 128 + b, g, H0, H1);                                \
        __syncthreads();                                                     \
        if ((SNXT_) < S_) {                                                  \
            GOFF_ = ((size_t)b * S_ + (SNXT_)) * F_ + f0 + (g << 3);         \
            X0_ = ((const float4*)(x + GOFF_))[0];                           \
            X1_ = ((const float4*)(x + GOFF_))[1];                           \
            N0_ = ((const float4*)(hgn + GOFF_))[0];                         \
            N1_ = ((const float4*)(hgn + GOFF_))[1];                         \
        }                                                                    \
        MFMA_SECTION                                                         \
        __syncthreads();                                                     \
    }

    // main loop, unrolled by 2 chunks (A at s, B at s+21); prefetch depth 2
    for (int s = sb; s < S_; s += 42) {
        DO_CHUNK(XA0, XA1, NA0, NA1, gA, s + 42);
        if (s + 21 < S_) {
            DO_CHUNK(XB0, XB1, NB0, NB1, gB, s + 63);
        }
    }
#undef DO_CHUNK
#undef MFMA_SECTION

    // ---- epilogue: LDS-transpose each 16-row band, coalesced float4 stores,
    //      plus diagonal atomics into sqw (enables merged loss kernel) ----
    float* T = (float*)LDS;                      // [32][196] f32
    const int PADW = 196;
    float* dst = part + (size_t)(EXCL ? bid : (bid % npart)) * GSZ;
    int lrb = (wr ? 16 : 0) + (qd << 2);
    int lr2 = tid >> 4;
#pragma unroll
    for (int i = 0; i < 6; ++i) {
        __syncthreads();
#pragma unroll
        for (int j = 0; j < 3; ++j) {
            int colb = wc + j * 16 + m;
#pragma unroll
            for (int r = 0; r < 4; ++r)
                T[(lrb + r) * PADW + colb] = acc[i][j][r];
        }
        __syncthreads();
        int grow = i * 16 + (lr2 & 15) + (lr2 >> 4) * 96;
#pragma unroll
        for (int k = 0; k < 3; ++k) {
            int c4 = k * 16 + (tid & 15);
            float4 vv = *(const float4*)&T[lr2 * PADW + (c4 << 2)];
            int o = grow * N3 + (c4 << 2);
            if (EXCL) {
                *(float4*)(dst + o) = vv;
            } else {
                atomicAdd(dst + o + 0, vv.x);
                atomicAdd(dst + o + 1, vv.y);
                atomicAdd(dst + o + 2, vv.z);
                atomicAdd(dst + o + 3, vv.w);
            }
        }
        if (tid < 32) {
            // diagonal of this 16-row band (T row tid holds global row dr, col dr)
            int dr = i * 16 + (tid & 15) + (tid >> 4) * 96;
            atomicAdd(sqw + dr, T[tid * PADW + dr]);
        }
    }
}

// ---------------- K3: merged row-reduce + triplet loss (k_red eliminated) ----------
// 192 blocks x 512 threads. Block i reduces Gram row i across npart partials into
// LDS, reads the precomputed diagonal sqw[], computes hard-pos/neg and the loss.
// r3 bug: SQS/LN loader used tid in [384,576) but blockDim=512 -> SQS[128..191]
// uninitialized. Fixed: loader range [320,512) = exactly 192 in-block threads.
__global__ void k_loss(const float* __restrict__ part, const float* __restrict__ sqw,
                       const int* __restrict__ labels,
                       float* __restrict__ out_loss, int npart) {
    __shared__ float ROW[2][N3];
    __shared__ float SQS[N3];
    __shared__ int   LN[N3];
    __shared__ float APW[3], ANW[3];
    int i = blockIdx.x, tid = threadIdx.x;
    if (tid < 384) {
        int c = tid % N3, h = tid / N3;
        float sacc = 0.f;
#pragma unroll 4
        for (int p = h; p < npart; p += 2)
            sacc += part[(size_t)p * GSZ + i * N3 + c];
        ROW[h][c] = sacc;
    }
    if (tid >= 320) {                            // tid in [320,512): 192 threads
        int c = tid - 320;
        SQS[c] = sqw[c];
        LN[c] = (c < 128) ? labels[c & 63] : -1;
    }
    __syncthreads();
    if (tid < N3) {
        float gij = ROW[0][tid] + ROW[1][tid];
        int li = LN[i];
        float d2 = SQS[i] + SQS[tid] - 2.0f * gij;
        float dist = sqrtf(fmaxf(d2, 1e-12f));
        bool pos = (li == LN[tid]);
        float ap = pos ? dist : -1e30f;
        float an = pos ? 1e30f : dist;
#pragma unroll
        for (int off = 32; off; off >>= 1) {
            ap = fmaxf(ap, __shfl_xor(ap, off));
            an = fminf(an, __shfl_xor(an, off));
        }
        if ((tid & 63) == 0) { APW[tid >> 6] = ap; ANW[tid >> 6] = an; }
    }
    __syncthreads();
    if (tid == 0) {
        float a = fmaxf(fmaxf(APW[0], APW[1]), APW[2]);
        float n = fminf(fminf(ANW[0], ANW[1]), ANW[2]);
        float xv = a - n;
        float sp = fmaxf(xv, 0.0f) + log1pf(expf(-fabsf(xv)));
        atomicAdd(out_loss, sp * (1.0f / (float)N3));
    }
}

extern "C" void kernel_launch(void* const* d_in, const int* in_sizes, int n_in,
                              void* d_out, int out_size, void* d_ws, size_t ws_size,
                              hipStream_t stream) {
    const float* x        = (const float*)d_in[0];
    const float* lmda     = (const float*)d_in[1];
    const float* mean_buf = (const float*)d_in[2];
    const float* var_buf  = (const float*)d_in[3];
    const float* hgn      = (const float*)d_in[4];
    const int*   labels   = (const int*)d_in[5];
    const int*   domain   = (const int*)d_in[6];
    const int*   d_rand   = (const int*)d_in[7];
    float* out = (float*)d_out;
    float* ws  = (float*)d_ws;

    long avail = (long)(ws_size / 4) - WS_PART;
    int npart = (int)(avail / GSZ);
    if (npart < 1) npart = 1;
    if (npart > GRID_MAIN) npart = GRID_MAIN;
    bool excl = (npart == GRID_MAIN);
    float* part = ws + WS_PART;
    float* sqw  = ws + WS_SQ;

    k_stats<<<dim3(192), dim3(512), 0, stream>>>(x, ws + WS_S1, ws + WS_S2,
                                                 sqw, out + OUT_LOSS);
    if (!excl) {
        hipMemsetAsync(part, 0, (size_t)npart * GSZ * 4, stream);
    }
    if (excl) {
        k_main<true><<<dim3(GRID_MAIN), dim3(512), 0, stream>>>(
            x, hgn, ws + WS_S1, ws + WS_S2, mean_buf, var_buf,
            lmda, domain, d_rand,
            out, out + OUT_NM, out + OUT_NV, part, sqw, npart);
    } else {
        k_main<false><<<dim3(GRID_MAIN), dim3(512), 0, stream>>>(
            x, hgn, ws + WS_S1, ws + WS_S2, mean_buf, var_buf,
            lmda, domain, d_rand,
            out, out + OUT_NM, out + OUT_NV, part, sqw, npart);
    }
    k_loss<<<dim3(N3), dim3(512), 0, stream>>>(part, sqw, labels,
                                               out + OUT_LOSS, npart);
}

// Round 5
// 141.284 us; speedup vs baseline: 1.8609x; 1.0042x over previous
//
#include <hip/hip_runtime.h>
#include <math.h>

#define B_ 64
#define S_ 129
#define F_ 768
#define N3 192            // 3*B
#define GSZ 36864         // 192*192
#define GRID_MAIN 252     // 12 f-columns x 21 s-groups

// ws float offsets
#define WS_S1   0
#define WS_S2   49152
#define WS_SQ   98304     // 192 floats (diag of gram), padded to 256
#define WS_PART 98560

// out float offsets
#define OUT_LOSS 6340608
#define OUT_NM   6340609
#define OUT_NV   6343681

typedef unsigned int uint;
using short8v = __attribute__((ext_vector_type(8))) short;
using float4v = __attribute__((ext_vector_type(4))) float;

// ---------------- bf16 helpers ----------------
__device__ __forceinline__ uint pack2(float a, float b) {
    uint ua = __float_as_uint(a);
    uint ub = __float_as_uint(b);
    uint ha = (ua + 0x7FFFu + ((ua >> 16) & 1u)) >> 16;
    uint hb = (ub + 0x7FFFu + ((ub >> 16) & 1u)) & 0xFFFF0000u;
    return hb | ha;
}

__device__ __forceinline__ void bf16_store8(char* lds, int row, int g,
                                            float4 v0, float4 v1) {
    uint4 H;
    H.x = pack2(v0.x, v0.y);
    H.y = pack2(v0.z, v0.w);
    H.z = pack2(v1.x, v1.y);
    H.w = pack2(v1.z, v1.w);
    *(uint4*)(lds + row * 128 + ((g ^ (row & 7)) << 4)) = H;
}

__device__ __forceinline__ float4 fma4(float4 a, float4 x, float4 b) {
    float4 r;
    r.x = fmaf(a.x, x.x, b.x); r.y = fmaf(a.y, x.y, b.y);
    r.z = fmaf(a.z, x.z, b.z); r.w = fmaf(a.w, x.w, b.w);
    return r;
}

// ---------------- K1: per-(b,f) sums over S, 8-way S-split + LDS reduce ------------
// Also zeroes sqw (gram diagonal accumulator) and out_loss.
__global__ void k_stats(const float* __restrict__ x,
                        float* __restrict__ s1, float* __restrict__ s2,
                        float* __restrict__ sqw, float* __restrict__ out_loss) {
    __shared__ float4 r1[512], r2[512];
    if (blockIdx.x == 0) {
        if (threadIdx.x == 0) out_loss[0] = 0.0f;
        if (threadIdx.x < N3) sqw[threadIdx.x] = 0.0f;
    }
    int b = blockIdx.x / 3, fg = blockIdx.x % 3;
    int c = threadIdx.x & 63, sp = threadIdx.x >> 6;   // 8-way S split
    int f = fg * 256 + c * 4;
    const float* p = x + (size_t)b * S_ * F_ + f;
    int s0 = sp * 16;
    int se = s0 + 16 + (sp == 7 ? 1 : 0);
    float4 a1 = {0.f,0.f,0.f,0.f}, a2 = {0.f,0.f,0.f,0.f};
#pragma unroll 4
    for (int s = s0; s < se; ++s) {
        float4 v = *(const float4*)(p + s * F_);
        a1.x += v.x; a1.y += v.y; a1.z += v.z; a1.w += v.w;
        a2.x += v.x*v.x; a2.y += v.y*v.y; a2.z += v.z*v.z; a2.w += v.w*v.w;
    }
    r1[threadIdx.x] = a1; r2[threadIdx.x] = a2;
    __syncthreads();
    if (sp == 0) {
        float4 t1 = r1[c], t2 = r2[c];
#pragma unroll
        for (int k = 1; k < 8; ++k) {
            float4 u1 = r1[k * 64 + c], u2 = r2[k * 64 + c];
            t1.x += u1.x; t1.y += u1.y; t1.z += u1.z; t1.w += u1.w;
            t2.x += u2.x; t2.y += u2.y; t2.z += u2.z; t2.w += u2.w;
        }
        *(float4*)(s1 + b * F_ + f) = t1;
        *(float4*)(s2 + b * F_ + f) = t2;
    }
}

// ---------------- K2: fused dom-stats + coef + x_mix/hg gen + MFMA Gram -------------
// 252 blocks x 512 threads, 1 block/CU. r5 change: TWO-CHUNK staging — chunks A and
// B go into two LDS planes (384 rows x 128 B = 48 KB), one barrier pair wraps a
// 72-MFMA section (K=128). Halves barrier count; register prefetch (depth-2, same
// regs as r4 — no spill-risk change) now has a full double-section to cover HBM
// latency. Epilogue also atomicAdds the partial-Gram diagonal into sqw.
template <bool EXCL>
__global__ __launch_bounds__(512, 2)
void k_main(const float* __restrict__ x, const float* __restrict__ hgn,
            const float* __restrict__ s1, const float* __restrict__ s2,
            const float* __restrict__ mean_buf, const float* __restrict__ var_buf,
            const float* __restrict__ lmda, const int* __restrict__ domain,
            const int* __restrict__ d_rand,
            float* __restrict__ xmix, float* __restrict__ out_nm,
            float* __restrict__ out_nv,
            float* part, float* __restrict__ sqw, int npart) {
    __shared__ __align__(16) char LDS[49152];   // 2 planes x 192 rows x 128 B
    __shared__ float NMV[4][64];
    __shared__ float SVV[4][64];

    int tid = threadIdx.x;
    int bid = blockIdx.x;
    int fc = bid % 12, sb = bid / 12;
    int f0 = fc * 64;
    int b = tid >> 3, g = tid & 7;
    int w = tid >> 6;
    int wr = (w >> 2) * 96, wc = (w & 3) * 48;
    int lane = tid & 63, m = lane & 15, qd = lane >> 4;

    // depth-2 prefetch: preload chunks sb (A) and sb+21 (B) before the prologue
    size_t gA = ((size_t)b * S_ + sb) * F_ + f0 + (g << 3);
    float4 XA0 = ((const float4*)(x + gA))[0];
    float4 XA1 = ((const float4*)(x + gA))[1];
    float4 NA0 = ((const float4*)(hgn + gA))[0];
    float4 NA1 = ((const float4*)(hgn + gA))[1];
    size_t gB = ((size_t)b * S_ + sb + 21) * F_ + f0 + (g << 3);  // sb+21 <= 41 < S_
    float4 XB0 = ((const float4*)(x + gB))[0];
    float4 XB1 = ((const float4*)(x + gB))[1];
    float4 NB0 = ((const float4*)(hgn + gB))[0];
    float4 NB1 = ((const float4*)(hgn + gB))[1];

    // ---- folded k_dom: per-(d,f) EMA stats for this block's f-column ----
    if (tid < 256) {
        int d = tid & 3, fl = tid >> 2;
        int f = f0 + fl;
        float a1 = 0.f, a2 = 0.f, cnt = 0.f;
#pragma unroll 8
        for (int bb = 0; bb < B_; ++bb) {
            bool mk = (domain[bb] == d);
            a1  += mk ? s1[bb * F_ + f] : 0.f;
            a2  += mk ? s2[bb * F_ + f] : 0.f;
            cnt += mk ? 1.f : 0.f;
        }
        float nm, nv;
        if (cnt > 0.f) {
            float n = cnt * (float)S_;
            float mu = a1 / n;
            float var = (a2 - n * mu * mu) / fmaxf(n - 1.f, 1.f);
            nm = 0.9f * mean_buf[d * F_ + f] + 0.1f * mu;
            nv = 0.9f * var_buf[d * F_ + f] + 0.1f * var;
        } else {
            nm = mean_buf[d * F_ + f];
            nv = var_buf[d * F_ + f];
        }
        NMV[d][fl] = nm;
        SVV[d][fl] = sqrtf(nv + 1e-6f);
        if (sb == 0) { out_nm[d * F_ + f] = nm; out_nv[d * F_ + f] = nv; }
    }
    __syncthreads();

    // ---- folded k_coef: per-thread mix/hg coefficients, held in regs all kernel ----
    int cb = b * F_ + f0 + (g << 3);
    float4 S1a = ((const float4*)(s1 + cb))[0], S1b = ((const float4*)(s1 + cb))[1];
    float4 S2a = ((const float4*)(s2 + cb))[0], S2b = ((const float4*)(s2 + cb))[1];
    int dm = domain[b];
    int dsd = (dm + d_rand[b]) & 3;              // D == 4
    float lam = lmda[b];
    float4 C1a, C1b, C0a, C0b, HMa, HMb, HSa, HSb;
#define COEF(SC1, SC2, FL, RC1, RC0, RHM, RHS) {            \
        float mu = (SC1) * (1.0f / (float)S_);              \
        float v  = ((SC2) - (float)S_ * mu * mu) * (1.0f / (float)(S_ - 1)); \
        float r  = rsqrtf(v + 1e-6f);                       \
        float sv = SVV[dsd][FL];                            \
        float rs = r * sv;                                  \
        RC1 = lam + (1.0f - lam) * rs;                      \
        RC0 = (1.0f - lam) * (NMV[dsd][FL] - mu * rs);      \
        RHM = NMV[dm][FL];                                  \
        RHS = SVV[dm][FL]; }
    {
        int fb = g << 3;
        COEF(S1a.x, S2a.x, fb + 0, C1a.x, C0a.x, HMa.x, HSa.x);
        COEF(S1a.y, S2a.y, fb + 1, C1a.y, C0a.y, HMa.y, HSa.y);
        COEF(S1a.z, S2a.z, fb + 2, C1a.z, C0a.z, HMa.z, HSa.z);
        COEF(S1a.w, S2a.w, fb + 3, C1a.w, C0a.w, HMa.w, HSa.w);
        COEF(S1b.x, S2b.x, fb + 4, C1b.x, C0b.x, HMb.x, HSb.x);
        COEF(S1b.y, S2b.y, fb + 5, C1b.y, C0b.y, HMb.y, HSb.y);
        COEF(S1b.z, S2b.z, fb + 6, C1b.z, C0b.z, HMb.z, HSb.z);
        COEF(S1b.w, S2b.w, fb + 7, C1b.w, C0b.w, HMb.w, HSb.w);
    }
#undef COEF

    float4v acc[6][3];
#pragma unroll
    for (int i = 0; i < 6; ++i)
#pragma unroll
        for (int j = 0; j < 3; ++j)
            acc[i][j] = (float4v){0.f, 0.f, 0.f, 0.f};

    // stage one chunk's three planes (x / x_mix / hg) into LDS plane PL
#define STAGE_CHUNK(PL, X0_, X1_, N0_, N1_, GOFF_)                           \
    {                                                                        \
        float4 M0 = fma4(C1a, X0_, C0a);                                     \
        float4 M1 = fma4(C1b, X1_, C0b);                                     \
        ((float4*)(xmix + GOFF_))[0] = M0;                                   \
        ((float4*)(xmix + GOFF_))[1] = M1;                                   \
        float4 H0 = fma4(HSa, N0_, HMa);                                     \
        float4 H1 = fma4(HSb, N1_, HMb);                                     \
        bf16_store8(LDS, (PL) * 192 + b, g, X0_, X1_);                       \
        bf16_store8(LDS, (PL) * 192 + 64 + b, g, M0, M1);                    \
        bf16_store8(LDS, (PL) * 192 + 128 + b, g, H0, H1);                   \
    }

    // 36 MFMAs over one plane (K=64, two k-granules of 32)
#define MFMA_PLANE(PL)                                                       \
        _Pragma("unroll")                                                    \
        for (int t = 0; t < 2; ++t) {                                        \
            short8v A[6];                                                    \
            _Pragma("unroll")                                                \
            for (int i = 0; i < 6; ++i) {                                    \
                int row = wr + i * 16 + m;                                   \
                int go = (((t << 2) + qd) ^ (row & 7)) << 4;                 \
                A[i] = *(const short8v*)(LDS + ((PL) * 192 + row) * 128 + go); \
            }                                                                \
            _Pragma("unroll")                                                \
            for (int j = 0; j < 3; ++j) {                                    \
                int row = wc + j * 16 + m;                                   \
                int go = (((t << 2) + qd) ^ (row & 7)) << 4;                 \
                short8v Bv = *(const short8v*)(LDS + ((PL) * 192 + row) * 128 + go); \
                _Pragma("unroll")                                            \
                for (int i = 0; i < 6; ++i)                                  \
                    acc[i][j] = __builtin_amdgcn_mfma_f32_16x16x32_bf16(     \
                        A[i], Bv, acc[i][j], 0, 0, 0);                       \
            }                                                                \
        }

    // main loop: 2 chunks per barrier pair (A at s, B at s+21); prefetch depth 2
    for (int s = sb; s < S_; s += 42) {
        bool haveB = (s + 21 < S_);              // block-uniform
        STAGE_CHUNK(0, XA0, XA1, NA0, NA1, gA);
        if (haveB) STAGE_CHUNK(1, XB0, XB1, NB0, NB1, gB);
        __syncthreads();

        if (s + 42 < S_) {
            gA = ((size_t)b * S_ + s + 42) * F_ + f0 + (g << 3);
            XA0 = ((const float4*)(x + gA))[0];
            XA1 = ((const float4*)(x + gA))[1];
            NA0 = ((const float4*)(hgn + gA))[0];
            NA1 = ((const float4*)(hgn + gA))[1];
        }
        if (s + 63 < S_) {
            gB = ((size_t)b * S_ + s + 63) * F_ + f0 + (g << 3);
            XB0 = ((const float4*)(x + gB))[0];
            XB1 = ((const float4*)(x + gB))[1];
            NB0 = ((const float4*)(hgn + gB))[0];
            NB1 = ((const float4*)(hgn + gB))[1];
        }

        MFMA_PLANE(0);
        if (haveB) MFMA_PLANE(1);
        __syncthreads();
    }
#undef STAGE_CHUNK
#undef MFMA_PLANE

    // ---- epilogue: LDS-transpose each 16-row band, coalesced float4 stores,
    //      plus diagonal atomics into sqw (enables merged loss kernel) ----
    float* T = (float*)LDS;                      // [32][196] f32 (reuses plane 0)
    const int PADW = 196;
    float* dst = part + (size_t)(EXCL ? bid : (bid % npart)) * GSZ;
    int lrb = (wr ? 16 : 0) + (qd << 2);
    int lr2 = tid >> 4;
#pragma unroll
    for (int i = 0; i < 6; ++i) {
        __syncthreads();
#pragma unroll
        for (int j = 0; j < 3; ++j) {
            int colb = wc + j * 16 + m;
#pragma unroll
            for (int r = 0; r < 4; ++r)
                T[(lrb + r) * PADW + colb] = acc[i][j][r];
        }
        __syncthreads();
        int grow = i * 16 + (lr2 & 15) + (lr2 >> 4) * 96;
#pragma unroll
        for (int k = 0; k < 3; ++k) {
            int c4 = k * 16 + (tid & 15);
            float4 vv = *(const float4*)&T[lr2 * PADW + (c4 << 2)];
            int o = grow * N3 + (c4 << 2);
            if (EXCL) {
                *(float4*)(dst + o) = vv;
            } else {
                atomicAdd(dst + o + 0, vv.x);
                atomicAdd(dst + o + 1, vv.y);
                atomicAdd(dst + o + 2, vv.z);
                atomicAdd(dst + o + 3, vv.w);
            }
        }
        if (tid < 32) {
            // diagonal of this 16-row band (T row tid holds global row dr, col dr)
            int dr = i * 16 + (tid & 15) + (tid >> 4) * 96;
            atomicAdd(sqw + dr, T[tid * PADW + dr]);
        }
    }
}

// ---------------- K3: merged row-reduce + triplet loss ----------------
// 192 blocks x 512 threads. Block i reduces Gram row i across npart partials into
// LDS, reads the precomputed diagonal sqw[], computes hard-pos/neg and the loss.
// (r3 bug fixed in r4: SQS/LN loader range [320,512) = exactly 192 in-block threads.)
__global__ void k_loss(const float* __restrict__ part, const float* __restrict__ sqw,
                       const int* __restrict__ labels,
                       float* __restrict__ out_loss, int npart) {
    __shared__ float ROW[2][N3];
    __shared__ float SQS[N3];
    __shared__ int   LN[N3];
    __shared__ float APW[3], ANW[3];
    int i = blockIdx.x, tid = threadIdx.x;
    if (tid < 384) {
        int c = tid % N3, h = tid / N3;
        float sacc = 0.f;
#pragma unroll 4
        for (int p = h; p < npart; p += 2)
            sacc += part[(size_t)p * GSZ + i * N3 + c];
        ROW[h][c] = sacc;
    }
    if (tid >= 320) {                            // tid in [320,512): 192 threads
        int c = tid - 320;
        SQS[c] = sqw[c];
        LN[c] = (c < 128) ? labels[c & 63] : -1;
    }
    __syncthreads();
    if (tid < N3) {
        float gij = ROW[0][tid] + ROW[1][tid];
        int li = LN[i];
        float d2 = SQS[i] + SQS[tid] - 2.0f * gij;
        float dist = sqrtf(fmaxf(d2, 1e-12f));
        bool pos = (li == LN[tid]);
        float ap = pos ? dist : -1e30f;
        float an = pos ? 1e30f : dist;
#pragma unroll
        for (int off = 32; off; off >>= 1) {
            ap = fmaxf(ap, __shfl_xor(ap, off));
            an = fminf(an, __shfl_xor(an, off));
        }
        if ((tid & 63) == 0) { APW[tid >> 6] = ap; ANW[tid >> 6] = an; }
    }
    __syncthreads();
    if (tid == 0) {
        float a = fmaxf(fmaxf(APW[0], APW[1]), APW[2]);
        float n = fminf(fminf(ANW[0], ANW[1]), ANW[2]);
        float xv = a - n;
        float sp = fmaxf(xv, 0.0f) + log1pf(expf(-fabsf(xv)));
        atomicAdd(out_loss, sp * (1.0f / (float)N3));
    }
}

extern "C" void kernel_launch(void* const* d_in, const int* in_sizes, int n_in,
                              void* d_out, int out_size, void* d_ws, size_t ws_size,
                              hipStream_t stream) {
    const float* x        = (const float*)d_in[0];
    const float* lmda     = (const float*)d_in[1];
    const float* mean_buf = (const float*)d_in[2];
    const float* var_buf  = (const float*)d_in[3];
    const float* hgn      = (const float*)d_in[4];
    const int*   labels   = (const int*)d_in[5];
    const int*   domain   = (const int*)d_in[6];
    const int*   d_rand   = (const int*)d_in[7];
    float* out = (float*)d_out;
    float* ws  = (float*)d_ws;

    long avail = (long)(ws_size / 4) - WS_PART;
    int npart = (int)(avail / GSZ);
    if (npart < 1) npart = 1;
    if (npart > GRID_MAIN) npart = GRID_MAIN;
    bool excl = (npart == GRID_MAIN);
    float* part = ws + WS_PART;
    float* sqw  = ws + WS_SQ;

    k_stats<<<dim3(192), dim3(512), 0, stream>>>(x, ws + WS_S1, ws + WS_S2,
                                                 sqw, out + OUT_LOSS);
    if (!excl) {
        hipMemsetAsync(part, 0, (size_t)npart * GSZ * 4, stream);
    }
    if (excl) {
        k_main<true><<<dim3(GRID_MAIN), dim3(512), 0, stream>>>(
            x, hgn, ws + WS_S1, ws + WS_S2, mean_buf, var_buf,
            lmda, domain, d_rand,
            out, out + OUT_NM, out + OUT_NV, part, sqw, npart);
    } else {
        k_main<false><<<dim3(GRID_MAIN), dim3(512), 0, stream>>>(
            x, hgn, ws + WS_S1, ws + WS_S2, mean_buf, var_buf,
            lmda, domain, d_rand,
            out, out + OUT_NM, out + OUT_NV, part, sqw, npart);
    }
    k_loss<<<dim3(N3), dim3(512), 0, stream>>>(part, sqw, labels,
                                               out + OUT_LOSS, npart);
}